// Round 3
// baseline (394.437 us; speedup 1.0000x reference)
//
#include <hip/hip_runtime.h>

// Laplacian pyramid L1 loss, (32,3,512,512) fp32, 5 levels.
// pyr_in[l]-pyr_tg[l] == pyramid(in-tg)[l] (linearity) -> one pyramid.
// upsample(conv 4K, zero-stuffed) == polyphase on down:
//   even-phase taps (.125,.75,.125), odd-phase (.5,.5) per axis.
// lap_level (levels 0,1): stage 71x71 tile -> LDS, 34x34 down tile
//   (float2 LDS reads, store 32x32 interior), separable up: 34x64
//   horizontal plane in LDS, then band with wave-uniform y-parity.
// lap_tail (levels 2,3,4): one block per plane, whole 128^2 plane in LDS.

#define BC 96
#define IST 72   // staged input stride (even -> float2 alias ok)
#define DST 36   // down tile stride

__device__ __forceinline__ int refl(int i, int n) {
    if (i < 0) i = -i;
    if (i >= n) i = 2 * n - 2 - i;
    return i;
}

__device__ __forceinline__ float wave_block_reduce(float v, float* red, int tid) {
#pragma unroll
    for (int off = 32; off > 0; off >>= 1)
        v += __shfl_down(v, off, 64);
    int lane = tid & 63, wid = tid >> 6;
    if (lane == 0) red[wid] = v;
    __syncthreads();
    return v;  // caller uses red[]
}

template<bool DIFF>
__global__ __launch_bounds__(256) void lap_level(
        const float* __restrict__ A, const float* __restrict__ B,
        float* __restrict__ down, float* __restrict__ out,
        int H, int Hd, int T, float invN) {
    __shared__ float sIn[71 * IST];
    __shared__ float sD[34 * DST];
    __shared__ float sUp[34 * 64];
    __shared__ float red[4];

    const int tid = threadIdx.x;
    const int lane = tid & 63, wid = tid >> 6;
    const int tt = blockIdx.x % (T * T);
    const int bc = blockIdx.x / (T * T);
    const int ty = tt / T, tx = tt % T;
    const size_t ibase = (size_t)bc * H * H;
    const int r0 = 64 * ty - 4, c0 = 64 * tx - 4;
    const int dy0 = 32 * ty - 1, dx0 = 32 * tx - 1;
    const bool xb = (tx == 0) | (tx == T - 1);

    // ---- stage 71x71 (diff at level 0). wave-uniform row, no div/mod ----
    const float* Ab = A + ibase;
    const float* Bb = DIFF ? (B + ibase) : nullptr;
    for (int r = wid; r < 71; r += 4) {
        int gr = r0 + r;
        gr = gr < 0 ? -gr : gr;
        gr = gr >= H ? 2 * H - 2 - gr : gr;
        const float* ar = Ab + (size_t)gr * H;
        const float* br = DIFF ? (Bb + (size_t)gr * H) : nullptr;
        float* srow = sIn + r * IST;
        if (!xb) {
            int gc = c0 + lane;
            float v = ar[gc];
            if (DIFF) v -= br[gc];
            srow[lane] = v;
            if (lane < 7) {
                float v2 = ar[gc + 64];
                if (DIFF) v2 -= br[gc + 64];
                srow[lane + 64] = v2;
            }
        } else {
            int gc = refl(c0 + lane, H);
            float v = ar[gc];
            if (DIFF) v -= br[gc];
            srow[lane] = v;
            if (lane < 7) {
                int gc2 = refl(c0 + lane + 64, H);
                float v2 = ar[gc2];
                if (DIFF) v2 -= br[gc2];
                srow[lane + 64] = v2;
            }
        }
    }
    __syncthreads();

    // ---- down 34x34 via float2 LDS reads (conflict-free) ----
    const float k0 = 0.0625f, k1 = 0.25f, k2 = 0.375f;
    float* dplane = down + (size_t)bc * Hd * Hd;
    for (int i = tid; i < 34 * 34; i += 256) {
        int dy = i / 34, dx = i - dy * 34;
        float acc = 0.f;
#pragma unroll
        for (int u = 0; u < 5; ++u) {
            const float2* p = (const float2*)(sIn + (2 * dy + u) * IST) + dx;
            float2 a = p[0], b = p[1], c = p[2];
            float rs = k0 * a.x + k1 * a.y + k2 * b.x + k1 * b.y + k0 * c.x;
            float ku = (u == 0 || u == 4) ? k0 : ((u == 2) ? k2 : k1);
            acc += ku * rs;
        }
        sD[dy * DST + dx] = acc;
        if (((unsigned)(dy - 1) < 32u) & ((unsigned)(dx - 1) < 32u))
            dplane[(size_t)(dy0 + dy) * Hd + (dx0 + dx)] = acc;
    }
    __syncthreads();

    // ---- horizontal up plane: 34 rows x 64 cols, pairwise, float2 writes ----
    {
        const bool xlo = (tx == 0), xhi = (tx == T - 1);
        for (int i = tid; i < 34 * 32; i += 256) {
            int a = i >> 5, j = i & 31;
            const float* dr = sD + a * DST;
            float d0 = dr[j], d1 = dr[j + 1], d2 = dr[j + 2];
            float d0e = (xlo && j == 0) ? d2 : d0;       // fx==0: taps {2,1,2}
            float d2e = (xhi && j == 31) ? d1 : d2;      // fx==H-2
            float d2o = (xhi && j == 31) ? d1 : d2;      // fx==H-1
            float2 w;
            w.x = 0.125f * d0e + 0.75f * d1 + 0.125f * d2e;
            w.y = 0.5f * (d1 + d2o);
            ((float2*)(sUp + a * 64))[j] = w;
        }
    }
    __syncthreads();

    // ---- band: wave-uniform y parity, 2-3 LDS reads + 3 FMA per px ----
    float local = 0.f;
    {
        const bool ylo = (ty == 0), yhi = (ty == T - 1);
        for (int i = tid; i < 4096; i += 256) {
            int ly = i >> 6, lx = i & 63;
            float cur = sIn[(ly + 4) * IST + (lx + 4)];
            int m = ly >> 1;
            float up;
            if ((ly & 1) == 0) {
                int a0 = (ylo && ly == 0) ? 2 : m;
                int a2 = (yhi && ly == 62) ? (m + 1) : (m + 2);
                up = 0.125f * sUp[a0 * 64 + lx] + 0.75f * sUp[(m + 1) * 64 + lx]
                   + 0.125f * sUp[a2 * 64 + lx];
            } else {
                int a2 = (yhi && ly == 63) ? (m + 1) : (m + 2);
                up = 0.5f * (sUp[(m + 1) * 64 + lx] + sUp[a2 * 64 + lx]);
            }
            local += fabsf(cur - up);
        }
    }

    wave_block_reduce(local, red, tid);
    if (tid == 0)
        atomicAdd(out, (red[0] + red[1] + red[2] + red[3]) * invN);
}

// ---- levels 2..4: one block per plane, plane lives in LDS ----
__global__ __launch_bounds__(1024) void lap_tail(
        const float* __restrict__ down1, float* __restrict__ out,
        float invN2, float invN3, float invN4) {
    __shared__ float sP[128 * 130];
    __shared__ float sD[64 * 66];
    __shared__ float red[16];

    const int tid = threadIdx.x;
    const int bc = blockIdx.x;
    const float* src = down1 + (size_t)bc * 128 * 128;
    for (int i = tid; i < 128 * 128; i += 1024) {
        int r = i >> 7, c = i & 127;
        sP[r * 130 + c] = src[i];
    }
    __syncthreads();

    const float K[5] = {0.0625f, 0.25f, 0.375f, 0.25f, 0.0625f};
    const int Hl[4] = {128, 64, 32, 16};
    const float invNs[3] = {invN2, invN3, invN4};
    float acc = 0.f;

#pragma unroll
    for (int l = 0; l < 3; ++l) {
        const int Hc = Hl[l], Hdc = Hl[l + 1];
        // down Hdc x Hdc
        for (int i = tid; i < Hdc * Hdc; i += 1024) {
            int y = i / Hdc, x = i - y * Hdc;
            int rows[5], cols[5];
#pragma unroll
            for (int u = 0; u < 5; ++u) {
                rows[u] = refl(2 * y + u - 2, Hc);
                cols[u] = refl(2 * x + u - 2, Hc);
            }
            float a = 0.f;
#pragma unroll
            for (int u = 0; u < 5; ++u) {
                const float* rp = sP + rows[u] * 130;
                a += K[u] * (K[0] * rp[cols[0]] + K[1] * rp[cols[1]] +
                             K[2] * rp[cols[2]] + K[3] * rp[cols[3]] +
                             K[4] * rp[cols[4]]);
            }
            sD[y * 66 + x] = a;
        }
        __syncthreads();
        // band Hc x Hc
        float lsum = 0.f;
        for (int i = tid; i < Hc * Hc; i += 1024) {
            int y = i / Hc, x = i - y * Hc;
            float cur = sP[y * 130 + x];
            int ax0, ax1, ax2; float wx0, wx1, wx2;
            if ((x & 1) == 0) {
                ax0 = refl(x - 2, Hc) >> 1; ax1 = x >> 1; ax2 = refl(x + 2, Hc) >> 1;
                wx0 = 0.125f; wx1 = 0.75f; wx2 = 0.125f;
            } else {
                ax0 = (x - 1) >> 1; ax1 = refl(x + 1, Hc) >> 1; ax2 = ax0;
                wx0 = 0.5f; wx1 = 0.5f; wx2 = 0.f;
            }
            int ay0, ay1, ay2; float wy0, wy1, wy2;
            if ((y & 1) == 0) {
                ay0 = refl(y - 2, Hc) >> 1; ay1 = y >> 1; ay2 = refl(y + 2, Hc) >> 1;
                wy0 = 0.125f; wy1 = 0.75f; wy2 = 0.125f;
            } else {
                ay0 = (y - 1) >> 1; ay1 = refl(y + 1, Hc) >> 1; ay2 = ay0;
                wy0 = 0.5f; wy1 = 0.5f; wy2 = 0.f;
            }
            const float* q0 = sD + ay0 * 66;
            const float* q1 = sD + ay1 * 66;
            const float* q2 = sD + ay2 * 66;
            float up = wy0 * (wx0 * q0[ax0] + wx1 * q0[ax1] + wx2 * q0[ax2]) +
                       wy1 * (wx0 * q1[ax0] + wx1 * q1[ax1] + wx2 * q1[ax2]) +
                       wy2 * (wx0 * q2[ax0] + wx1 * q2[ax1] + wx2 * q2[ax2]);
            lsum += fabsf(cur - up);
        }
        acc += lsum * invNs[l];
        __syncthreads();
        if (l < 2) {
            for (int i = tid; i < Hdc * Hdc; i += 1024) {
                int y = i / Hdc, x = i - y * Hdc;
                sP[y * 130 + x] = sD[y * 66 + x];
            }
            __syncthreads();
        }
    }

#pragma unroll
    for (int off = 32; off > 0; off >>= 1)
        acc += __shfl_down(acc, off, 64);
    int lane = tid & 63, wid = tid >> 6;
    if (lane == 0) red[wid] = acc;
    __syncthreads();
    if (tid == 0) {
        float s = 0.f;
#pragma unroll
        for (int i = 0; i < 16; ++i) s += red[i];
        atomicAdd(out, s);
    }
}

extern "C" void kernel_launch(void* const* d_in, const int* in_sizes, int n_in,
                              void* d_out, int out_size, void* d_ws, size_t ws_size,
                              hipStream_t stream) {
    const float* in = (const float*)d_in[0];
    const float* tg = (const float*)d_in[1];
    float* out = (float*)d_out;
    float* ws = (float*)d_ws;

    float* down0 = ws;                       // 96*256*256
    float* down1 = down0 + (size_t)BC * 256 * 256;  // 96*128*128

    hipMemsetAsync(out, 0, sizeof(float), stream);

    // level 0: H=512, Hd=256, T=8
    lap_level<true><<<BC * 64, 256, 0, stream>>>(
        in, tg, down0, out, 512, 256, 8, 1.f / (96.f * 512.f * 512.f));
    // level 1: H=256, Hd=128, T=4
    lap_level<false><<<BC * 16, 256, 0, stream>>>(
        down0, nullptr, down1, out, 256, 128, 4, 1.f / (96.f * 256.f * 256.f));
    // levels 2-4 fused
    lap_tail<<<BC, 1024, 0, stream>>>(
        down1, out,
        1.f / (96.f * 128.f * 128.f),
        1.f / (96.f * 64.f * 64.f),
        1.f / (96.f * 32.f * 32.f));
}

// Round 4
// 273.077 us; speedup vs baseline: 1.4444x; 1.4444x over previous
//
#include <hip/hip_runtime.h>

// Laplacian pyramid L1 loss, (32,3,512,512) fp32, 5 levels.
// pyramid(in)-pyramid(tg) == pyramid(in-tg) (linearity) -> one pyramid.
// upsample(conv 4K on zero-stuffed) == polyphase on down:
//   even phase taps (.125,.75,.125), odd phase (.5,.5) per axis.
// lap_slide: wave-owned line-sliding pipeline. One wave = one R-row strip of
// one plane; lane owns NC=W/64 contiguous cols. Horizontal 5-tap via lane
// shuffles, vertical 5-tap via 5-row register ring, up via 3-row W register
// ring. No LDS traffic, no barriers, no div/mod. Band rows re-read cur from
// global (L1/L2 hit; HBM unchanged).
// lap_small: levels 3+4, one 256-thr block per plane, compile-time sizes.

#define BC 96
#define KA 0.0625f
#define KB 0.25f
#define KC 0.375f

__device__ __forceinline__ int refl(int i, int n) {
    if (i < 0) i = -i;
    if (i >= n) i = 2 * n - 2 - i;
    return i;
}

template<int H, int NC, bool DIFF>
__device__ __forceinline__ void load_row(const float* __restrict__ pa,
                                         const float* __restrict__ pb,
                                         int r, int basec, float* __restrict__ c) {
    const int off = r * H + basec;
    if constexpr (NC == 8) {
        float4 a0 = *(const float4*)(pa + off);
        float4 a1 = *(const float4*)(pa + off + 4);
        c[0]=a0.x; c[1]=a0.y; c[2]=a0.z; c[3]=a0.w;
        c[4]=a1.x; c[5]=a1.y; c[6]=a1.z; c[7]=a1.w;
        if constexpr (DIFF) {
            float4 b0 = *(const float4*)(pb + off);
            float4 b1 = *(const float4*)(pb + off + 4);
            c[0]-=b0.x; c[1]-=b0.y; c[2]-=b0.z; c[3]-=b0.w;
            c[4]-=b1.x; c[5]-=b1.y; c[6]-=b1.z; c[7]-=b1.w;
        }
    } else if constexpr (NC == 4) {
        float4 a0 = *(const float4*)(pa + off);
        c[0]=a0.x; c[1]=a0.y; c[2]=a0.z; c[3]=a0.w;
        if constexpr (DIFF) {
            float4 b0 = *(const float4*)(pb + off);
            c[0]-=b0.x; c[1]-=b0.y; c[2]-=b0.z; c[3]-=b0.w;
        }
    } else {
        float2 a0 = *(const float2*)(pa + off);
        c[0]=a0.x; c[1]=a0.y;
        if constexpr (DIFF) {
            float2 b0 = *(const float2*)(pb + off);
            c[0]-=b0.x; c[1]-=b0.y;
        }
    }
}

// horizontal 5-tap at even cols. c = own NC cols; o = ND outputs.
// ext[x] = col (basec + x - 2); halos via shuffles with reflect fixups.
template<int NC>
__device__ __forceinline__ void hconv(const float* __restrict__ c,
                                      float* __restrict__ o, int lane) {
    constexpr int ND = NC / 2;
    float e[NC + 3];
#pragma unroll
    for (int i = 0; i < NC; ++i) e[i + 2] = c[i];
    const bool l0 = (lane == 0), l63 = (lane == 63);
    // col basec-1: lane-1's last own; lane0 -> own col 1 (e[3])
    { float v = __shfl(e[NC + 1], lane - 1); e[1] = l0 ? e[3] : v; }
    if constexpr (NC >= 4) {
        { float v = __shfl(e[NC], lane - 1); e[0] = l0 ? e[4] : v; }          // col basec-2 | refl-> col2
        { float v = __shfl(e[2], lane + 1); e[NC + 2] = l63 ? e[NC] : v; }    // col basec+NC | refl-> H-2
    } else {
        e[0] = __shfl(e[2], l0 ? 1 : lane - 1);
        e[NC + 2] = __shfl(e[2], l63 ? 63 : lane + 1);
    }
#pragma unroll
    for (int j = 0; j < ND; ++j)
        o[j] = KA * e[2*j] + KB * e[2*j+1] + KC * e[2*j+2]
             + KB * e[2*j+3] + KA * e[2*j+4];
}

template<int H, int NC, bool DIFF, int R>
__global__ __launch_bounds__(256) void lap_slide(
        const float* __restrict__ A, const float* __restrict__ B,
        float* __restrict__ down, float* __restrict__ out, float invN) {
    constexpr int Hd = H / 2, ND = NC / 2, SPP = H / R;
    __shared__ float red[4];
    const int tid = threadIdx.x;
    const int lane = tid & 63, wid = tid >> 6;
    const int sid = blockIdx.x * 4 + wid;
    const int bc = sid / SPP;
    const int y0 = (sid % SPP) * R;
    const float* pa = A + (size_t)bc * H * H;
    const float* pb = DIFF ? (B + (size_t)bc * H * H) : nullptr;
    float* pd = down + (size_t)bc * Hd * Hd;
    const int basec = lane * NC;

    float h0[ND], h1[ND], h2[ND], h3[ND], h4[ND];
    float w0[NC], w1[NC], w2[NC];
#pragma unroll
    for (int i = 0; i < NC; ++i) { w0[i] = 0.f; w1[i] = 0.f; w2[i] = 0.f; }
    float acc = 0.f;
    float c[NC];

    const int d0 = y0 >> 1;
    int dbeg = d0 - 1; if (dbeg < 0) dbeg = 0;
    const int dend = d0 + R / 2;

    // prologue: htmp rows 2*dbeg-2 .. 2*dbeg
    load_row<H,NC,DIFF>(pa, pb, refl(2*dbeg - 2, H), basec, c); hconv<NC>(c, h0, lane);
    load_row<H,NC,DIFF>(pa, pb, refl(2*dbeg - 1, H), basec, c); hconv<NC>(c, h1, lane);
    load_row<H,NC,DIFF>(pa, pb, refl(2*dbeg,     H), basec, c); hconv<NC>(c, h2, lane);

    for (int d = dbeg; d <= dend; ++d) {
        load_row<H,NC,DIFF>(pa, pb, refl(2*d + 1, H), basec, c); hconv<NC>(c, h3, lane);
        load_row<H,NC,DIFF>(pa, pb, refl(2*d + 2, H), basec, c); hconv<NC>(c, h4, lane);

        float dn[ND];
#pragma unroll
        for (int j = 0; j < ND; ++j)
            dn[j] = KA*h0[j] + KB*h1[j] + KC*h2[j] + KB*h3[j] + KA*h4[j];

        if (d >= d0 && d < d0 + R/2) {
            const int doff = d * Hd + lane * ND;
            if constexpr (ND == 4) {
                float4 s; s.x = dn[0]; s.y = dn[1]; s.z = dn[2]; s.w = dn[3];
                *(float4*)(pd + doff) = s;
            } else if constexpr (ND == 2) {
                float2 s; s.x = dn[0]; s.y = dn[1];
                *(float2*)(pd + doff) = s;
            } else {
                pd[doff] = dn[0];
            }
        }

        // horizontal-up row W[d] from dn (+ halos with reflect fixups)
        float dm, dp;
        if constexpr (ND >= 2) {
            { float v = __shfl(dn[ND-1], lane - 1); dm = (lane == 0)  ? dn[1]    : v; }
            { float v = __shfl(dn[0],    lane + 1); dp = (lane == 63) ? dn[ND-1] : v; }
        } else {
            dm = __shfl(dn[0], (lane == 0)  ? 1  : lane - 1);
            dp = __shfl(dn[0], (lane == 63) ? 63 : lane + 1);
        }
#pragma unroll
        for (int i = 0; i < NC; ++i) { w0[i] = w1[i]; w1[i] = w2[i]; }
#pragma unroll
        for (int j = 0; j < ND; ++j) {
            float lf = j ? dn[j-1] : dm;
            float rg = (j + 1 < ND) ? dn[j+1] : dp;
            w2[2*j]     = 0.125f * lf + 0.75f * dn[j] + 0.125f * rg;
            w2[2*j + 1] = 0.5f * (dn[j] + rg);
        }

        // emit band rows 2d-2 (even), 2d-1 (odd)
        if (d >= d0 + 1) {
            const int ye = 2 * d - 2;
            float ce[NC], co[NC];
            load_row<H,NC,DIFF>(pa, pb, ye,     basec, ce);
            load_row<H,NC,DIFF>(pa, pb, ye + 1, basec, co);
            if (ye == 0) {
#pragma unroll
                for (int i = 0; i < NC; ++i) {
                    acc += fabsf(ce[i] - (0.75f*w1[i] + 0.25f*w2[i]));
                    acc += fabsf(co[i] - 0.5f*(w1[i] + w2[i]));
                }
            } else if (ye == H - 2) {
#pragma unroll
                for (int i = 0; i < NC; ++i) {
                    acc += fabsf(ce[i] - (0.125f*w0[i] + 0.875f*w1[i]));
                    acc += fabsf(co[i] - w1[i]);
                }
            } else {
#pragma unroll
                for (int i = 0; i < NC; ++i) {
                    acc += fabsf(ce[i] - (0.125f*w0[i] + 0.75f*w1[i] + 0.125f*w2[i]));
                    acc += fabsf(co[i] - 0.5f*(w1[i] + w2[i]));
                }
            }
        }
#pragma unroll
        for (int j = 0; j < ND; ++j) { h0[j] = h2[j]; h1[j] = h3[j]; h2[j] = h4[j]; }
    }

#pragma unroll
    for (int off2 = 32; off2 > 0; off2 >>= 1)
        acc += __shfl_down(acc, off2, 64);
    if (lane == 0) red[wid] = acc;
    __syncthreads();
    if (tid == 0)
        atomicAdd(out, (red[0] + red[1] + red[2] + red[3]) * invN);
}

// ---- levels 3 (64->32) and 4 (32->16): one block per plane ----
__global__ __launch_bounds__(256) void lap_small(
        const float* __restrict__ dsrc, float* __restrict__ out,
        float invN3, float invN4) {
    __shared__ float p[64 * 66];
    __shared__ float hh[64 * 34];
    __shared__ float dd[32 * 34];
    __shared__ float W3[32 * 64];
    __shared__ float h4[32 * 18];
    __shared__ float d4[16 * 18];
    __shared__ float W4[16 * 32];
    __shared__ float red[4];
    const int tid = threadIdx.x;
    const float* src = dsrc + (size_t)blockIdx.x * 4096;
    for (int i = tid; i < 4096; i += 256)
        p[(i >> 6) * 66 + (i & 63)] = src[i];
    __syncthreads();
    const float k[5] = {KA, KB, KC, KB, KA};
    for (int i = tid; i < 64 * 32; i += 256) {
        int r = i >> 5, t = i & 31;
        const float* pr = p + r * 66;
        float s = 0.f;
#pragma unroll
        for (int v = 0; v < 5; ++v) s += k[v] * pr[refl(2*t + v - 2, 64)];
        hh[r * 34 + t] = s;
    }
    __syncthreads();
    for (int i = tid; i < 32 * 32; i += 256) {
        int dy = i >> 5, t = i & 31;
        float s = 0.f;
#pragma unroll
        for (int u = 0; u < 5; ++u) s += k[u] * hh[refl(2*dy + u - 2, 64) * 34 + t];
        dd[dy * 34 + t] = s;
    }
    __syncthreads();
    for (int i = tid; i < 32 * 32; i += 256) {
        int a = i >> 5, t = i & 31;
        const float* dr = dd + a * 34;
        float dm = dr[t == 0 ? 1 : t - 1];
        float dc = dr[t];
        float dp = dr[t == 31 ? 31 : t + 1];
        W3[a * 64 + 2*t]     = 0.125f * dm + 0.75f * dc + 0.125f * dp;
        W3[a * 64 + 2*t + 1] = 0.5f * (dc + dp);
    }
    __syncthreads();
    float acc3 = 0.f;
    for (int i = tid; i < 4096; i += 256) {
        int y = i >> 6, x = i & 63;
        float cur = p[y * 66 + x];
        float up;
        if ((y & 1) == 0) {
            int a0 = refl(y - 2, 64) >> 1, a1 = y >> 1, a2 = refl(y + 2, 64) >> 1;
            up = 0.125f*W3[a0*64 + x] + 0.75f*W3[a1*64 + x] + 0.125f*W3[a2*64 + x];
        } else {
            int a0 = (y - 1) >> 1, a1 = refl(y + 1, 64) >> 1;
            up = 0.5f * (W3[a0*64 + x] + W3[a1*64 + x]);
        }
        acc3 += fabsf(cur - up);
    }
    __syncthreads();
    for (int i = tid; i < 32 * 16; i += 256) {
        int r = i >> 4, t = i & 15;
        const float* pr = dd + r * 34;
        float s = 0.f;
#pragma unroll
        for (int v = 0; v < 5; ++v) s += k[v] * pr[refl(2*t + v - 2, 32)];
        h4[r * 18 + t] = s;
    }
    __syncthreads();
    for (int i = tid; i < 16 * 16; i += 256) {
        int dy = i >> 4, t = i & 15;
        float s = 0.f;
#pragma unroll
        for (int u = 0; u < 5; ++u) s += k[u] * h4[refl(2*dy + u - 2, 32) * 18 + t];
        d4[dy * 18 + t] = s;
    }
    __syncthreads();
    for (int i = tid; i < 16 * 16; i += 256) {
        int a = i >> 4, t = i & 15;
        const float* dr = d4 + a * 18;
        float dm = dr[t == 0 ? 1 : t - 1];
        float dc = dr[t];
        float dp = dr[t == 15 ? 15 : t + 1];
        W4[a * 32 + 2*t]     = 0.125f * dm + 0.75f * dc + 0.125f * dp;
        W4[a * 32 + 2*t + 1] = 0.5f * (dc + dp);
    }
    __syncthreads();
    float acc4 = 0.f;
    for (int i = tid; i < 1024; i += 256) {
        int y = i >> 5, x = i & 31;
        float cur = dd[y * 34 + x];
        float up;
        if ((y & 1) == 0) {
            int a0 = refl(y - 2, 32) >> 1, a1 = y >> 1, a2 = refl(y + 2, 32) >> 1;
            up = 0.125f*W4[a0*32 + x] + 0.75f*W4[a1*32 + x] + 0.125f*W4[a2*32 + x];
        } else {
            int a0 = (y - 1) >> 1, a1 = refl(y + 1, 32) >> 1;
            up = 0.5f * (W4[a0*32 + x] + W4[a1*32 + x]);
        }
        acc4 += fabsf(cur - up);
    }
    float acc = acc3 * invN3 + acc4 * invN4;
#pragma unroll
    for (int off2 = 32; off2 > 0; off2 >>= 1)
        acc += __shfl_down(acc, off2, 64);
    int lane = tid & 63, wid = tid >> 6;
    if (lane == 0) red[wid] = acc;
    __syncthreads();
    if (tid == 0)
        atomicAdd(out, red[0] + red[1] + red[2] + red[3]);
}

extern "C" void kernel_launch(void* const* d_in, const int* in_sizes, int n_in,
                              void* d_out, int out_size, void* d_ws, size_t ws_size,
                              hipStream_t stream) {
    const float* in = (const float*)d_in[0];
    const float* tg = (const float*)d_in[1];
    float* out = (float*)d_out;
    float* ws = (float*)d_ws;

    float* down0 = ws;                                   // 96*256*256
    float* down1 = down0 + (size_t)BC * 256 * 256;       // 96*128*128
    float* down2 = down1 + (size_t)BC * 128 * 128;       // 96*64*64

    hipMemsetAsync(out, 0, sizeof(float), stream);

    // strips = 96*(H/16); 4 waves (strips) per 256-thr block
    lap_slide<512, 8, true, 16><<<96 * 32 / 4, 256, 0, stream>>>(
        in, tg, down0, out, 1.f / (96.f * 512.f * 512.f));
    lap_slide<256, 4, false, 16><<<96 * 16 / 4, 256, 0, stream>>>(
        down0, nullptr, down1, out, 1.f / (96.f * 256.f * 256.f));
    lap_slide<128, 2, false, 16><<<96 * 8 / 4, 256, 0, stream>>>(
        down1, nullptr, down2, out, 1.f / (96.f * 128.f * 128.f));
    lap_small<<<BC, 256, 0, stream>>>(
        down2, out, 1.f / (96.f * 64.f * 64.f), 1.f / (96.f * 32.f * 32.f));
}

// Round 5
// 261.402 us; speedup vs baseline: 1.5089x; 1.0447x over previous
//
#include <hip/hip_runtime.h>

// Laplacian pyramid L1 loss, (32,3,512,512) fp32, 5 levels.
// pyramid(in)-pyramid(tg) == pyramid(in-tg) (linearity) -> one pyramid.
// upsample(conv 4K on zero-stuffed) == polyphase on down:
//   even phase taps (.125,.75,.125), odd phase (.5,.5) per axis.
// lap_slide: wave-owned line-sliding pipeline. One wave = one R-row strip.
// Lane owns NC=W/64 cols. Horizontal 5-tap via shuffles, vertical via 5-row
// register ring, up via 3-row W ring. Band rows come from a 3-row raw-row
// register ring (NO global re-read). Next iteration's rows are prefetched
// (raw A/B regs) one full iteration ahead -> load latency hidden by compute.
// lap_small: levels 3+4, one 1024-thr block per plane.

#define BC 96
#define KA 0.0625f
#define KB 0.25f
#define KC 0.375f

__device__ __forceinline__ int refl(int i, int n) {
    if (i < 0) i = -i;
    if (i >= n) i = 2 * n - 2 - i;
    return i;
}

// raw row load: A into a[], B into b[] (DIFF only). No subtraction here.
template<int H, int NC, bool DIFF>
__device__ __forceinline__ void load_raw(const float* __restrict__ pa,
                                         const float* __restrict__ pb,
                                         int r, int basec,
                                         float* __restrict__ a,
                                         float* __restrict__ b) {
    const int off = r * H + basec;
    if constexpr (NC == 8) {
        float4 a0 = *(const float4*)(pa + off);
        float4 a1 = *(const float4*)(pa + off + 4);
        a[0]=a0.x; a[1]=a0.y; a[2]=a0.z; a[3]=a0.w;
        a[4]=a1.x; a[5]=a1.y; a[6]=a1.z; a[7]=a1.w;
        if constexpr (DIFF) {
            float4 b0 = *(const float4*)(pb + off);
            float4 b1 = *(const float4*)(pb + off + 4);
            b[0]=b0.x; b[1]=b0.y; b[2]=b0.z; b[3]=b0.w;
            b[4]=b1.x; b[5]=b1.y; b[6]=b1.z; b[7]=b1.w;
        }
    } else if constexpr (NC == 4) {
        float4 a0 = *(const float4*)(pa + off);
        a[0]=a0.x; a[1]=a0.y; a[2]=a0.z; a[3]=a0.w;
        if constexpr (DIFF) {
            float4 b0 = *(const float4*)(pb + off);
            b[0]=b0.x; b[1]=b0.y; b[2]=b0.z; b[3]=b0.w;
        }
    } else {
        float2 a0 = *(const float2*)(pa + off);
        a[0]=a0.x; a[1]=a0.y;
        if constexpr (DIFF) {
            float2 b0 = *(const float2*)(pb + off);
            b[0]=b0.x; b[1]=b0.y;
        }
    }
}

template<int NC, bool DIFF>
__device__ __forceinline__ void materialize(const float* __restrict__ a,
                                            const float* __restrict__ b,
                                            float* __restrict__ c) {
#pragma unroll
    for (int i = 0; i < NC; ++i) c[i] = DIFF ? (a[i] - b[i]) : a[i];
}

// horizontal 5-tap at even cols. c = own NC cols; o = ND outputs.
template<int NC>
__device__ __forceinline__ void hconv(const float* __restrict__ c,
                                      float* __restrict__ o, int lane) {
    constexpr int ND = NC / 2;
    float e[NC + 3];
#pragma unroll
    for (int i = 0; i < NC; ++i) e[i + 2] = c[i];
    const bool l0 = (lane == 0), l63 = (lane == 63);
    { float v = __shfl(e[NC + 1], lane - 1); e[1] = l0 ? e[3] : v; }
    if constexpr (NC >= 4) {
        { float v = __shfl(e[NC], lane - 1); e[0] = l0 ? e[4] : v; }
        { float v = __shfl(e[2], lane + 1); e[NC + 2] = l63 ? e[NC] : v; }
    } else {
        e[0] = __shfl(e[2], l0 ? 1 : lane - 1);
        e[NC + 2] = __shfl(e[2], l63 ? 63 : lane + 1);
    }
#pragma unroll
    for (int j = 0; j < ND; ++j)
        o[j] = KA * e[2*j] + KB * e[2*j+1] + KC * e[2*j+2]
             + KB * e[2*j+3] + KA * e[2*j+4];
}

template<int H, int NC, bool DIFF, int R>
__global__ __launch_bounds__(256) void lap_slide(
        const float* __restrict__ A, const float* __restrict__ B,
        float* __restrict__ down, float* __restrict__ out, float invN) {
    constexpr int Hd = H / 2, ND = NC / 2, SPP = H / R;
    __shared__ float red[4];
    const int tid = threadIdx.x;
    const int lane = tid & 63, wid = tid >> 6;
    const int sid = blockIdx.x * 4 + wid;
    const int bc = sid / SPP;
    const int y0 = (sid % SPP) * R;
    const float* pa = A + (size_t)bc * H * H;
    const float* pb = DIFF ? (B + (size_t)bc * H * H) : nullptr;
    float* pd = down + (size_t)bc * Hd * Hd;
    const int basec = lane * NC;

    float h0[ND], h1[ND], h2[ND], h3[ND], h4[ND];
    float w0[NC], w1[NC], w2[NC];
    float eOld[NC], eMid[NC], oPrev[NC];      // raw-row ring for band
    float nA1[NC], nB1[NC], nA2[NC], nB2[NC]; // prefetch regs
    float c1[NC], c2[NC], t[NC], tb[NC];
#pragma unroll
    for (int i = 0; i < NC; ++i) {
        w0[i] = 0.f; w1[i] = 0.f; w2[i] = 0.f;
        eOld[i] = 0.f; oPrev[i] = 0.f;
    }
    float acc = 0.f;

    const int d0 = y0 >> 1;
    int dbeg = d0 - 1; if (dbeg < 0) dbeg = 0;
    const int dend = d0 + R / 2;

    // prologue: rows 2dbeg-2, 2dbeg-1, 2dbeg
    load_raw<H,NC,DIFF>(pa, pb, refl(2*dbeg - 2, H), basec, t, tb);
    materialize<NC,DIFF>(t, tb, c1); hconv<NC>(c1, h0, lane);
    load_raw<H,NC,DIFF>(pa, pb, refl(2*dbeg - 1, H), basec, t, tb);
    materialize<NC,DIFF>(t, tb, c1); hconv<NC>(c1, h1, lane);
    load_raw<H,NC,DIFF>(pa, pb, refl(2*dbeg, H), basec, t, tb);
    materialize<NC,DIFF>(t, tb, eMid); hconv<NC>(eMid, h2, lane);
    // prefetch rows for d = dbeg
    load_raw<H,NC,DIFF>(pa, pb, refl(2*dbeg + 1, H), basec, nA1, nB1);
    load_raw<H,NC,DIFF>(pa, pb, refl(2*dbeg + 2, H), basec, nA2, nB2);

    for (int d = dbeg; d <= dend; ++d) {
        // materialize current rows, then immediately issue next-iter loads
        materialize<NC,DIFF>(nA1, nB1, c1);
        materialize<NC,DIFF>(nA2, nB2, c2);
        load_raw<H,NC,DIFF>(pa, pb, refl(2*d + 3, H), basec, nA1, nB1);
        load_raw<H,NC,DIFF>(pa, pb, refl(2*d + 4, H), basec, nA2, nB2);

        hconv<NC>(c1, h3, lane);
        hconv<NC>(c2, h4, lane);

        float dn[ND];
#pragma unroll
        for (int j = 0; j < ND; ++j)
            dn[j] = KA*h0[j] + KB*h1[j] + KC*h2[j] + KB*h3[j] + KA*h4[j];

        if (d >= d0 && d < d0 + R/2) {
            const int doff = d * Hd + lane * ND;
            if constexpr (ND == 4) {
                float4 s; s.x=dn[0]; s.y=dn[1]; s.z=dn[2]; s.w=dn[3];
                *(float4*)(pd + doff) = s;
            } else if constexpr (ND == 2) {
                float2 s; s.x=dn[0]; s.y=dn[1];
                *(float2*)(pd + doff) = s;
            } else {
                pd[doff] = dn[0];
            }
        }

        // horizontal-up row W[d]
        float dm, dp;
        if constexpr (ND >= 2) {
            { float v = __shfl(dn[ND-1], lane - 1); dm = (lane == 0)  ? dn[1]    : v; }
            { float v = __shfl(dn[0],    lane + 1); dp = (lane == 63) ? dn[ND-1] : v; }
        } else {
            dm = __shfl(dn[0], (lane == 0)  ? 1  : lane - 1);
            dp = __shfl(dn[0], (lane == 63) ? 63 : lane + 1);
        }
#pragma unroll
        for (int i = 0; i < NC; ++i) { w0[i] = w1[i]; w1[i] = w2[i]; }
#pragma unroll
        for (int j = 0; j < ND; ++j) {
            float lf = j ? dn[j-1] : dm;
            float rg = (j + 1 < ND) ? dn[j+1] : dp;
            w2[2*j]     = 0.125f * lf + 0.75f * dn[j] + 0.125f * rg;
            w2[2*j + 1] = 0.5f * (dn[j] + rg);
        }

        // band rows 2d-2 (even, from eOld), 2d-1 (odd, from oPrev)
        if (d >= d0 + 1) {
            const int ye = 2 * d - 2;
            if (ye == 0) {
#pragma unroll
                for (int i = 0; i < NC; ++i) {
                    acc += fabsf(eOld[i]  - (0.75f*w1[i] + 0.25f*w2[i]));
                    acc += fabsf(oPrev[i] - 0.5f*(w1[i] + w2[i]));
                }
            } else if (ye == H - 2) {
#pragma unroll
                for (int i = 0; i < NC; ++i) {
                    acc += fabsf(eOld[i]  - (0.125f*w0[i] + 0.875f*w1[i]));
                    acc += fabsf(oPrev[i] - w1[i]);
                }
            } else {
#pragma unroll
                for (int i = 0; i < NC; ++i) {
                    acc += fabsf(eOld[i]  - (0.125f*w0[i] + 0.75f*w1[i] + 0.125f*w2[i]));
                    acc += fabsf(oPrev[i] - 0.5f*(w1[i] + w2[i]));
                }
            }
        }

        // shift rings
#pragma unroll
        for (int i = 0; i < NC; ++i) {
            eOld[i] = eMid[i]; eMid[i] = c2[i]; oPrev[i] = c1[i];
        }
#pragma unroll
        for (int j = 0; j < ND; ++j) { h0[j] = h2[j]; h1[j] = h3[j]; h2[j] = h4[j]; }
    }

#pragma unroll
    for (int off2 = 32; off2 > 0; off2 >>= 1)
        acc += __shfl_down(acc, off2, 64);
    if (lane == 0) red[wid] = acc;
    __syncthreads();
    if (tid == 0)
        atomicAdd(out, (red[0] + red[1] + red[2] + red[3]) * invN);
}

// ---- levels 3 (64->32) and 4 (32->16): one 1024-thr block per plane ----
__global__ __launch_bounds__(1024) void lap_small(
        const float* __restrict__ dsrc, float* __restrict__ out,
        float invN3, float invN4) {
    __shared__ float p[64 * 66];
    __shared__ float hh[64 * 34];
    __shared__ float dd[32 * 34];
    __shared__ float W3[32 * 64];
    __shared__ float h4[32 * 18];
    __shared__ float d4[16 * 18];
    __shared__ float W4[16 * 32];
    __shared__ float red[16];
    const int tid = threadIdx.x;
    const float* src = dsrc + (size_t)blockIdx.x * 4096;
    for (int i = tid; i < 4096; i += 1024)
        p[(i >> 6) * 66 + (i & 63)] = src[i];
    __syncthreads();
    const float k[5] = {KA, KB, KC, KB, KA};
    for (int i = tid; i < 64 * 32; i += 1024) {
        int r = i >> 5, t = i & 31;
        const float* pr = p + r * 66;
        float s = 0.f;
#pragma unroll
        for (int v = 0; v < 5; ++v) s += k[v] * pr[refl(2*t + v - 2, 64)];
        hh[r * 34 + t] = s;
    }
    __syncthreads();
    for (int i = tid; i < 32 * 32; i += 1024) {
        int dy = i >> 5, t = i & 31;
        float s = 0.f;
#pragma unroll
        for (int u = 0; u < 5; ++u) s += k[u] * hh[refl(2*dy + u - 2, 64) * 34 + t];
        dd[dy * 34 + t] = s;
    }
    __syncthreads();
    for (int i = tid; i < 32 * 32; i += 1024) {
        int a = i >> 5, t = i & 31;
        const float* dr = dd + a * 34;
        float dm = dr[t == 0 ? 1 : t - 1];
        float dc = dr[t];
        float dp = dr[t == 31 ? 31 : t + 1];
        W3[a * 64 + 2*t]     = 0.125f * dm + 0.75f * dc + 0.125f * dp;
        W3[a * 64 + 2*t + 1] = 0.5f * (dc + dp);
    }
    __syncthreads();
    float acc3 = 0.f;
    for (int i = tid; i < 4096; i += 1024) {
        int y = i >> 6, x = i & 63;
        float cur = p[y * 66 + x];
        float up;
        if ((y & 1) == 0) {
            int a0 = refl(y - 2, 64) >> 1, a1 = y >> 1, a2 = refl(y + 2, 64) >> 1;
            up = 0.125f*W3[a0*64 + x] + 0.75f*W3[a1*64 + x] + 0.125f*W3[a2*64 + x];
        } else {
            int a0 = (y - 1) >> 1, a1 = refl(y + 1, 64) >> 1;
            up = 0.5f * (W3[a0*64 + x] + W3[a1*64 + x]);
        }
        acc3 += fabsf(cur - up);
    }
    __syncthreads();
    for (int i = tid; i < 32 * 16; i += 1024) {
        int r = i >> 4, t = i & 15;
        const float* pr = dd + r * 34;
        float s = 0.f;
#pragma unroll
        for (int v = 0; v < 5; ++v) s += k[v] * pr[refl(2*t + v - 2, 32)];
        h4[r * 18 + t] = s;
    }
    __syncthreads();
    for (int i = tid; i < 16 * 16; i += 1024) {
        int dy = i >> 4, t = i & 15;
        float s = 0.f;
#pragma unroll
        for (int u = 0; u < 5; ++u) s += k[u] * h4[refl(2*dy + u - 2, 32) * 18 + t];
        d4[dy * 18 + t] = s;
    }
    __syncthreads();
    for (int i = tid; i < 16 * 16; i += 1024) {
        int a = i >> 4, t = i & 15;
        const float* dr = d4 + a * 18;
        float dm = dr[t == 0 ? 1 : t - 1];
        float dc = dr[t];
        float dp = dr[t == 15 ? 15 : t + 1];
        W4[a * 32 + 2*t]     = 0.125f * dm + 0.75f * dc + 0.125f * dp;
        W4[a * 32 + 2*t + 1] = 0.5f * (dc + dp);
    }
    __syncthreads();
    float acc4 = 0.f;
    for (int i = tid; i < 1024; i += 1024) {
        int y = i >> 5, x = i & 31;
        float cur = dd[y * 34 + x];
        float up;
        if ((y & 1) == 0) {
            int a0 = refl(y - 2, 32) >> 1, a1 = y >> 1, a2 = refl(y + 2, 32) >> 1;
            up = 0.125f*W4[a0*32 + x] + 0.75f*W4[a1*32 + x] + 0.125f*W4[a2*32 + x];
        } else {
            int a0 = (y - 1) >> 1, a1 = refl(y + 1, 32) >> 1;
            up = 0.5f * (W4[a0*32 + x] + W4[a1*32 + x]);
        }
        acc4 += fabsf(cur - up);
    }
    float acc = acc3 * invN3 + acc4 * invN4;
#pragma unroll
    for (int off2 = 32; off2 > 0; off2 >>= 1)
        acc += __shfl_down(acc, off2, 64);
    int lane = tid & 63, wid = tid >> 6;
    if (lane == 0) red[wid] = acc;
    __syncthreads();
    if (tid == 0) {
        float s = 0.f;
#pragma unroll
        for (int i = 0; i < 16; ++i) s += red[i];
        atomicAdd(out, s);
    }
}

extern "C" void kernel_launch(void* const* d_in, const int* in_sizes, int n_in,
                              void* d_out, int out_size, void* d_ws, size_t ws_size,
                              hipStream_t stream) {
    const float* in = (const float*)d_in[0];
    const float* tg = (const float*)d_in[1];
    float* out = (float*)d_out;
    float* ws = (float*)d_ws;

    float* down0 = ws;                                   // 96*256*256
    float* down1 = down0 + (size_t)BC * 256 * 256;       // 96*128*128
    float* down2 = down1 + (size_t)BC * 128 * 128;       // 96*64*64

    hipMemsetAsync(out, 0, sizeof(float), stream);

    // level 0: 96*32 strips (R=16), 4 waves/block
    lap_slide<512, 8, true, 16><<<96 * 32 / 4, 256, 0, stream>>>(
        in, tg, down0, out, 1.f / (96.f * 512.f * 512.f));
    // level 1: R=8 -> 96*32 strips
    lap_slide<256, 4, false, 8><<<96 * 32 / 4, 256, 0, stream>>>(
        down0, nullptr, down1, out, 1.f / (96.f * 256.f * 256.f));
    // level 2: R=4 -> 96*32 strips
    lap_slide<128, 2, false, 4><<<96 * 32 / 4, 256, 0, stream>>>(
        down1, nullptr, down2, out, 1.f / (96.f * 128.f * 128.f));
    // levels 3+4
    lap_small<<<BC, 1024, 0, stream>>>(
        down2, out, 1.f / (96.f * 64.f * 64.f), 1.f / (96.f * 32.f * 32.f));
}